// Round 2
// baseline (637.646 us; speedup 1.0000x reference)
//
#include <hip/hip_runtime.h>
#include <cstdint>
#include <cstddef>

// Problem constants (B=4, S=4096, D=1024, Din=2048)
#define BB 4
#define SS 4096
#define DD 1024
#define DIN 2048
#define MTOT (BB*SS)        // 16384 rows
#define K1 DD               // GEMM1 K = 1024
#define K2 DIN              // GEMM2 K = 2048
#define N2 DD               // GEMM2 N = 1024
#define NCH (BB*DIN)        // 8192 scan channels
#define NCHUNK 32
#define CLEN (SS/NCHUNK)    // 128

typedef _Float16 half8  __attribute__((ext_vector_type(8)));
typedef _Float16 half4v __attribute__((ext_vector_type(4)));
typedef float    floatx4 __attribute__((ext_vector_type(4)));

#define AS1(p) ((__attribute__((address_space(1))) void*)(uintptr_t)(p))
#define AS3(p) ((__attribute__((address_space(3))) void*)(uint32_t)(uintptr_t)(p))

__device__ __forceinline__ void gload16(const void* g, void* l) {
  // async global->LDS, 16B/lane; LDS dest = wave-uniform base + lane*16
  __builtin_amdgcn_global_load_lds(AS1(g), AS3(l), 16, 0, 0);
}

__device__ __forceinline__ float sigm(float x) { return 1.f / (1.f + __expf(-x)); }
__device__ __forceinline__ uint32_t hbits(float f) {
  _Float16 h = (_Float16)f; uint16_t u; __builtin_memcpy(&u, &h, 2); return (uint32_t)u;
}
__device__ __forceinline__ float h_lo(uint32_t v) {
  uint16_t u = (uint16_t)(v & 0xffffu); _Float16 h; __builtin_memcpy(&h, &u, 2); return (float)h;
}
__device__ __forceinline__ float h_hi(uint32_t v) {
  uint16_t u = (uint16_t)(v >> 16); _Float16 h; __builtin_memcpy(&h, &u, 2); return (float)h;
}

// ---------------- elementwise converts ----------------

__global__ void f32_to_f16_vec(const float* __restrict__ src, _Float16* __restrict__ dst) {
  int i = (blockIdx.x * blockDim.x + threadIdx.x) * 4;
  float4 v = *(const float4*)(src + i);
  half4v o; o.x = (_Float16)v.x; o.y = (_Float16)v.y; o.z = (_Float16)v.z; o.w = (_Float16)v.w;
  *(half4v*)(dst + i) = o;
}

// src[R][C] f32 -> dst[C][R] f16
__global__ void transpose_cvt(const float* __restrict__ src, _Float16* __restrict__ dst,
                              int R, int C) {
  __shared__ float t[32][33];
  int c0 = blockIdx.x * 32, r0 = blockIdx.y * 32;
  int tx = threadIdx.x, ty = threadIdx.y;
#pragma unroll
  for (int j = 0; j < 32; j += 8)
    t[ty + j][tx] = src[(size_t)(r0 + ty + j) * C + c0 + tx];
  __syncthreads();
#pragma unroll
  for (int j = 0; j < 32; j += 8)
    dst[(size_t)(c0 + ty + j) * R + r0 + tx] = (_Float16)t[tx][ty + j];
}

// ---------------- GEMM1: x @ W1 fused with gate math ----------------
// AITER-style K-loop: 4-deep LDS ring, prefetch distance 2, raw s_barrier
// (no compiler vmcnt(0) drain), manual s_waitcnt vmcnt(10) = wait only for
// tile `it` (tiles it+1, it+2 stay in flight). WAR-safe: buffer it&3 is
// rewritten at iter it+2, after barrier it+1 which all waves reach only
// after their tile-it ds_reads completed (lgkm waits precede their MFMAs).
// Tail iters issue harmless dummy loads (stay branch-free, constant vmcnt);
// they read <=1.2KB past the tensor into the adjacent ws buffer.
//
// LDS swizzle: per-row k-group XOR swz(r) = (r>>1)&3 (applied to the GLOBAL
// source address; gload_lds dest stays linear). Read slot = 4r + (q^swz(r))
// -> bank-set 4(r&1) | (q ^ ((r>>1)&3)) covers all 8 sets 2x per 16-lane
// quarter = conflict-free b128. (Old swz(r)=r&3 hit only 2 sets 4x.)
__global__ __launch_bounds__(256) void gemm1_fused(
    const _Float16* __restrict__ xh, const _Float16* __restrict__ w1t,
    const float* __restrict__ b1, uint32_t* __restrict__ zg) {
  __shared__ _Float16 As[4][128 * 32];      // 4 x 8KB
  __shared__ _Float16 Bs[4][3][64 * 32];    // 4 x 12KB ; 80KB total

  const int tid = threadIdx.x;
  const int wave = tid >> 6, lane = tid & 63;
  const int wm = wave >> 1, wn = wave & 1;     // 2x2 waves: 64 rows x 32 cols/gate
  // XCD-chunked block swizzle (T1): dispatch order is round-robin over XCDs,
  // so XCD k gets flat = k, k+8, ... -> swz = 512k..512k+511 contiguous:
  // each XCD owns 16 m-blocks (A hot-set 512KB, L2-resident) with bx fast.
  const int flat = blockIdx.y * 32 + blockIdx.x;   // 4096 blocks, %8 == 0
  const int bswz = (flat & 7) * 512 + (flat >> 3);
  const int m0 = (bswz >> 5) * 128;
  const int d0 = (bswz & 31) * 64;
  const int lrow = lane >> 2;                              // staged row in chunk
  const int lk = (((lane & 3) ^ ((lrow >> 1) & 3)) * 8);   // staged k offset (halfs)
  const int roff = ((((lane & 15) << 2) | ((lane >> 4) ^ ((lane >> 1) & 3))) * 8); // read offset

  const _Float16* pA0 = xh + (size_t)(m0 + (wave * 2 + 0) * 16 + lrow) * K1 + lk;
  const _Float16* pA1 = pA0 + (size_t)16 * K1;
  const _Float16* pB0 = w1t + (size_t)(d0 + wave * 16 + lrow) * K1 + lk;
  const _Float16* pB1 = pB0 + (size_t)DIN * K1;
  const _Float16* pB2 = pB1 + (size_t)DIN * K1;

  floatx4 acc[3][4][2] = {};

  // prime tiles 0,1
#pragma unroll
  for (int t = 0; t < 2; ++t) {
    gload16(pA0 + t * 32, &As[t][(wave * 2 + 0) * 512]);
    gload16(pA1 + t * 32, &As[t][(wave * 2 + 1) * 512]);
    gload16(pB0 + t * 32, &Bs[t][0][wave * 512]);
    gload16(pB1 + t * 32, &Bs[t][1][wave * 512]);
    gload16(pB2 + t * 32, &Bs[t][2][wave * 512]);
  }
  pA0 += 64; pA1 += 64; pB0 += 64; pB1 += 64; pB2 += 64;

  for (int ito = 0; ito < K1 / 32 / 4; ++ito) {
#pragma unroll
    for (int ii = 0; ii < 4; ++ii) {
      const int sb = (ii + 2) & 3, rb = ii;
      gload16(pA0, &As[sb][(wave * 2 + 0) * 512]);
      gload16(pA1, &As[sb][(wave * 2 + 1) * 512]);
      gload16(pB0, &Bs[sb][0][wave * 512]);
      gload16(pB1, &Bs[sb][1][wave * 512]);
      gload16(pB2, &Bs[sb][2][wave * 512]);
      pA0 += 32; pA1 += 32; pB0 += 32; pB1 += 32; pB2 += 32;

      asm volatile("s_waitcnt vmcnt(10)" ::: "memory");
      __builtin_amdgcn_s_barrier();
      asm volatile("" ::: "memory");

      half8 af[4], bfr[3][2];
#pragma unroll
      for (int mi = 0; mi < 4; ++mi)
        af[mi] = *(const half8*)(&As[rb][(wm * 4 + mi) * 512 + roff]);
#pragma unroll
      for (int gt = 0; gt < 3; ++gt)
#pragma unroll
        for (int ni = 0; ni < 2; ++ni)
          bfr[gt][ni] = *(const half8*)(&Bs[rb][gt][(wn * 2 + ni) * 512 + roff]);
#pragma unroll
      for (int gt = 0; gt < 3; ++gt)
#pragma unroll
        for (int mi = 0; mi < 4; ++mi)
#pragma unroll
          for (int ni = 0; ni < 2; ++ni)
            acc[gt][mi][ni] = __builtin_amdgcn_mfma_f32_16x16x32_f16(
                af[mi], bfr[gt][ni], acc[gt][mi][ni], 0, 0, 0);
    }
  }

  // epilogue: bias + gate math, write packed (z,g)
  // z = sigma(softplus(-f)-softplus(-i)) = u/(u+v), u=1+e^-f, v=1+e^-i
#pragma unroll
  for (int ni = 0; ni < 2; ++ni) {
    int d = d0 + wn * 32 + ni * 16 + (lane & 15);
    float bh = b1[d], bf_ = b1[DIN + d], bi = b1[2 * DIN + d];
#pragma unroll
    for (int mi = 0; mi < 4; ++mi) {
#pragma unroll
      for (int r = 0; r < 4; ++r) {
        int m = m0 + wm * 64 + mi * 16 + (lane >> 4) * 4 + r;
        float hv = acc[0][mi][ni][r] + bh;
        float fv = acc[1][mi][ni][r] + bf_;
        float iv = acc[2][mi][ni][r] + bi;
        float u = 1.f + __expf(-fminf(fmaxf(fv, -30.f), 30.f));
        float v = 1.f + __expf(-fminf(fmaxf(iv, -30.f), 30.f));
        float z = __fdividef(u, u + v);
        float gg = (hv >= 0.f) ? (hv + 0.5f)
                               : __fdividef(1.f, 1.f + __expf(-fmaxf(hv, -30.f)));
        zg[(size_t)m * DIN + d] = hbits(z) | (hbits(gg) << 16);
      }
    }
  }
}

// ---------------- chunked parallel scan: h_t = (1-z) h + z g ----------------

__global__ void scanA(const uint32_t* __restrict__ zg,
                      float* __restrict__ cA, float* __restrict__ cB) {
  int gidx = blockIdx.x * 256 + threadIdx.x;
  int q = gidx >> 13, c = gidx & (NCH - 1);
  int b = c >> 11, d = c & (DIN - 1);
  size_t base = ((size_t)b * SS + q * CLEN) * DIN + d;
  float A = 1.f, Bv = 0.f;
#pragma unroll 4
  for (int t = 0; t < CLEN; ++t) {
    uint32_t v = zg[base + (size_t)t * DIN];
    float z = h_lo(v), g = h_hi(v);
    A *= (1.f - z);
    Bv = fmaf(z, g - Bv, Bv);
  }
  cA[q * NCH + c] = A;
  cB[q * NCH + c] = Bv;
}

__global__ void scanB(const float* __restrict__ cA, const float* __restrict__ cB,
                      const float* __restrict__ init_h, float* __restrict__ cH) {
  int c = blockIdx.x * 256 + threadIdx.x;  // 8192 channels
  int d = c & (DIN - 1);
  float x = init_h[d];
  float h = (x >= 0.f) ? (x + 0.5f) : sigm(x);  // h0 = g(init_h)
#pragma unroll
  for (int q = 0; q < NCHUNK; ++q) {
    cH[q * NCH + c] = h;                        // h at START of chunk q
    h = fmaf(cA[q * NCH + c], h, cB[q * NCH + c]);
  }
}

__global__ void scanC(const uint32_t* __restrict__ zg, const float* __restrict__ cH,
                      _Float16* __restrict__ hh, float* __restrict__ out_tail) {
  int gidx = blockIdx.x * 256 + threadIdx.x;
  int q = gidx >> 13, c = gidx & (NCH - 1);
  int b = c >> 11, d = c & (DIN - 1);
  size_t base = ((size_t)b * SS + q * CLEN) * DIN + d;
  float h = cH[q * NCH + c];
#pragma unroll 4
  for (int t = 0; t < CLEN; ++t) {
    uint32_t v = zg[base + (size_t)t * DIN];
    float z = h_lo(v), g = h_hi(v);
    h = fmaf(z, g - h, h);
    hh[base + (size_t)t * DIN] = (_Float16)h;
  }
  if (q == NCHUNK - 1) {
    out_tail[c] = h;             // next_hidden
    out_tail[NCH + c] = logf(h); // next_log_hidden
  }
}

// ---------------- GEMM2: out_h @ W2 + b2 (128x128, ring-pipelined) ---------
__global__ __launch_bounds__(256) void gemm2k(
    const _Float16* __restrict__ hh, const _Float16* __restrict__ w2t,
    const float* __restrict__ b2, float* __restrict__ out) {
  __shared__ _Float16 As[4][128 * 32];   // 4 x 8KB
  __shared__ _Float16 Bs[4][128 * 32];   // 4 x 8KB ; 64KB total

  const int tid = threadIdx.x;
  const int wave = tid >> 6, lane = tid & 63;
  const int wm = wave >> 1, wn = wave & 1;     // 2x2 waves: 64x64 each
  // XCD-chunked block swizzle (T1): 1024 blocks, 128 per XCD = 16 m-blocks.
  const int flat = blockIdx.y * 8 + blockIdx.x;
  const int bswz = (flat & 7) * 128 + (flat >> 3);
  const int m0 = (bswz >> 3) * 128;
  const int n0 = (bswz & 7) * 128;
  const int lrow = lane >> 2;
  const int lk = (((lane & 3) ^ ((lrow >> 1) & 3)) * 8);   // conflict-free swz (see gemm1)
  const int roff = ((((lane & 15) << 2) | ((lane >> 4) ^ ((lane >> 1) & 3))) * 8);

  const _Float16* pA0 = hh + (size_t)(m0 + (wave * 2 + 0) * 16 + lrow) * K2 + lk;
  const _Float16* pA1 = pA0 + (size_t)16 * K2;
  const _Float16* pB0 = w2t + (size_t)(n0 + (wave * 2 + 0) * 16 + lrow) * K2 + lk;
  const _Float16* pB1 = pB0 + (size_t)16 * K2;

  floatx4 acc[4][4] = {};

#pragma unroll
  for (int t = 0; t < 2; ++t) {
    gload16(pA0 + t * 32, &As[t][(wave * 2 + 0) * 512]);
    gload16(pA1 + t * 32, &As[t][(wave * 2 + 1) * 512]);
    gload16(pB0 + t * 32, &Bs[t][(wave * 2 + 0) * 512]);
    gload16(pB1 + t * 32, &Bs[t][(wave * 2 + 1) * 512]);
  }
  pA0 += 64; pA1 += 64; pB0 += 64; pB1 += 64;

  for (int ito = 0; ito < K2 / 32 / 4; ++ito) {
#pragma unroll
    for (int ii = 0; ii < 4; ++ii) {
      const int sb = (ii + 2) & 3, rb = ii;
      gload16(pA0, &As[sb][(wave * 2 + 0) * 512]);
      gload16(pA1, &As[sb][(wave * 2 + 1) * 512]);
      gload16(pB0, &Bs[sb][(wave * 2 + 0) * 512]);
      gload16(pB1, &Bs[sb][(wave * 2 + 1) * 512]);
      pA0 += 32; pA1 += 32; pB0 += 32; pB1 += 32;

      asm volatile("s_waitcnt vmcnt(8)" ::: "memory");
      __builtin_amdgcn_s_barrier();
      asm volatile("" ::: "memory");

      half8 af[4], bfr[4];
#pragma unroll
      for (int mi = 0; mi < 4; ++mi)
        af[mi] = *(const half8*)(&As[rb][(wm * 4 + mi) * 512 + roff]);
#pragma unroll
      for (int ni = 0; ni < 4; ++ni)
        bfr[ni] = *(const half8*)(&Bs[rb][(wn * 4 + ni) * 512 + roff]);
#pragma unroll
      for (int mi = 0; mi < 4; ++mi)
#pragma unroll
        for (int ni = 0; ni < 4; ++ni)
          acc[mi][ni] = __builtin_amdgcn_mfma_f32_16x16x32_f16(af[mi], bfr[ni], acc[mi][ni], 0, 0, 0);
    }
  }

#pragma unroll
  for (int ni = 0; ni < 4; ++ni) {
    int n = n0 + wn * 64 + ni * 16 + (lane & 15);
    float bias = b2[n];
#pragma unroll
    for (int mi = 0; mi < 4; ++mi) {
#pragma unroll
      for (int r = 0; r < 4; ++r) {
        int m = m0 + wm * 64 + mi * 16 + (lane >> 4) * 4 + r;
        out[(size_t)m * N2 + n] = acc[mi][ni][r] + bias;
      }
    }
  }
}

// ---------------- launch ----------------

extern "C" void kernel_launch(void* const* d_in, const int* in_sizes, int n_in,
                              void* d_out, int out_size, void* d_ws, size_t ws_size,
                              hipStream_t stream) {
  const float* x      = (const float*)d_in[0];
  const float* W1     = (const float*)d_in[1];
  const float* b1     = (const float*)d_in[2];
  const float* W2     = (const float*)d_in[3];
  const float* b2     = (const float*)d_in[4];
  const float* init_h = (const float*)d_in[5];
  float* out = (float*)d_out;

  char* w = (char*)d_ws;
  _Float16* xh  = (_Float16*)w; w += (size_t)MTOT * K1 * 2;       // 32 MB
  _Float16* w1t = (_Float16*)w; w += (size_t)3 * DIN * K1 * 2;    // 12 MB
  _Float16* w2t = (_Float16*)w; w += (size_t)N2 * K2 * 2;         // 4 MB
  uint32_t* zg  = (uint32_t*)w; w += (size_t)MTOT * DIN * 4;      // 128 MB
  _Float16* hh  = (_Float16*)w; w += (size_t)MTOT * DIN * 2;      // 64 MB
  float* cA = (float*)w; w += (size_t)NCH * NCHUNK * 4;
  float* cB = (float*)w; w += (size_t)NCH * NCHUNK * 4;
  float* cH = (float*)w; w += (size_t)NCH * NCHUNK * 4;

  f32_to_f16_vec<<<dim3(MTOT * K1 / 1024), dim3(256), 0, stream>>>(x, xh);
  transpose_cvt<<<dim3(3 * DIN / 32, K1 / 32), dim3(32, 8), 0, stream>>>(W1, w1t, K1, 3 * DIN);
  transpose_cvt<<<dim3(N2 / 32, K2 / 32), dim3(32, 8), 0, stream>>>(W2, w2t, K2, N2);

  gemm1_fused<<<dim3(DIN / 64, MTOT / 128), dim3(256), 0, stream>>>(xh, w1t, b1, zg);

  scanA<<<dim3(NCH * NCHUNK / 256), dim3(256), 0, stream>>>(zg, cA, cB);
  scanB<<<dim3(NCH / 256), dim3(256), 0, stream>>>(cA, cB, init_h, cH);
  scanC<<<dim3(NCH * NCHUNK / 256), dim3(256), 0, stream>>>(zg, cH, hh, out + (size_t)MTOT * DD);

  gemm2k<<<dim3(N2 / 128, MTOT / 128), dim3(256), 0, stream>>>(hh, w2t, b2, out);
}

// Round 3
// 577.105 us; speedup vs baseline: 1.1049x; 1.1049x over previous
//
#include <hip/hip_runtime.h>
#include <cstdint>
#include <cstddef>

// Problem constants (B=4, S=4096, D=1024, Din=2048)
#define BB 4
#define SS 4096
#define DD 1024
#define DIN 2048
#define MTOT (BB*SS)        // 16384 rows
#define K1 DD               // GEMM1 K = 1024
#define K2 DIN              // GEMM2 K = 2048
#define N2 DD               // GEMM2 N = 1024
#define NCH (BB*DIN)        // 8192 scan channels
#define NCHUNK 32
#define CLEN (SS/NCHUNK)    // 128

typedef _Float16 half8  __attribute__((ext_vector_type(8)));
typedef _Float16 half4v __attribute__((ext_vector_type(4)));
typedef float    floatx4 __attribute__((ext_vector_type(4)));

#define AS1(p) ((__attribute__((address_space(1))) void*)(uintptr_t)(p))
#define AS3(p) ((__attribute__((address_space(3))) void*)(uint32_t)(uintptr_t)(p))

__device__ __forceinline__ void gload16(const void* g, void* l) {
  // async global->LDS, 16B/lane; LDS dest = wave-uniform base + lane*16
  __builtin_amdgcn_global_load_lds(AS1(g), AS3(l), 16, 0, 0);
}

__device__ __forceinline__ float sigm(float x) { return 1.f / (1.f + __expf(-x)); }
__device__ __forceinline__ uint32_t hbits(float f) {
  _Float16 h = (_Float16)f; uint16_t u; __builtin_memcpy(&u, &h, 2); return (uint32_t)u;
}
__device__ __forceinline__ float h_lo(uint32_t v) {
  uint16_t u = (uint16_t)(v & 0xffffu); _Float16 h; __builtin_memcpy(&h, &u, 2); return (float)h;
}
__device__ __forceinline__ float h_hi(uint32_t v) {
  uint16_t u = (uint16_t)(v >> 16); _Float16 h; __builtin_memcpy(&h, &u, 2); return (float)h;
}

// ---------------- elementwise converts ----------------

__global__ void f32_to_f16_vec(const float* __restrict__ src, _Float16* __restrict__ dst) {
  int i = (blockIdx.x * blockDim.x + threadIdx.x) * 4;
  float4 v = *(const float4*)(src + i);
  half4v o; o.x = (_Float16)v.x; o.y = (_Float16)v.y; o.z = (_Float16)v.z; o.w = (_Float16)v.w;
  *(half4v*)(dst + i) = o;
}

// src[R][C] f32 -> dst[C][R] f16
__global__ void transpose_cvt(const float* __restrict__ src, _Float16* __restrict__ dst,
                              int R, int C) {
  __shared__ float t[32][33];
  int c0 = blockIdx.x * 32, r0 = blockIdx.y * 32;
  int tx = threadIdx.x, ty = threadIdx.y;
#pragma unroll
  for (int j = 0; j < 32; j += 8)
    t[ty + j][tx] = src[(size_t)(r0 + ty + j) * C + c0 + tx];
  __syncthreads();
#pragma unroll
  for (int j = 0; j < 32; j += 8)
    dst[(size_t)(c0 + ty + j) * R + r0 + tx] = (_Float16)t[tx][ty + j];
}

// ---------------- GEMM1: x @ W1 fused with gate math ----------------
// AITER-style K-loop: 4-deep LDS ring, prefetch distance 2, raw s_barrier
// (no compiler vmcnt(0) drain), manual s_waitcnt vmcnt(10) = wait only for
// tile `it` (tiles it+1, it+2 stay in flight). WAR-safe: buffer it&3 is
// rewritten at iter it+2, after barrier it+1 which all waves reach only
// after their tile-it ds_reads completed (lgkm waits precede their MFMAs).
// Tail iters issue harmless dummy loads (stay branch-free, constant vmcnt);
// they read <=1.2KB past the tensor into the adjacent ws buffer.
//
// LDS swizzle: per-row k-group XOR swz(r) = (r>>1)&3 (applied to the GLOBAL
// source address; gload_lds dest stays linear). Read slot = 4r + (q^swz(r))
// -> bank-set 4(r&1) | (q ^ ((r>>1)&3)) covers all 8 sets 2x per 16-lane
// quarter = conflict-free b128. (Measured r2: SQ_LDS_BANK_CONFLICT = 0.)
//
// Block order: NATURAL raster (bx fast). Measured r2: XCD-chunked remap
// tripled HBM FETCH (234->808 MB) -- co-resident blocks sharing consecutive
// m-panels + same B-sweep phase across ALL XCDs is what keeps A/B L3-hot.
// Do not re-introduce block swizzles here without watching FETCH_SIZE.
__global__ __launch_bounds__(256) void gemm1_fused(
    const _Float16* __restrict__ xh, const _Float16* __restrict__ w1t,
    const float* __restrict__ b1, uint32_t* __restrict__ zg) {
  __shared__ _Float16 As[4][128 * 32];      // 4 x 8KB
  __shared__ _Float16 Bs[4][3][64 * 32];    // 4 x 12KB ; 80KB total

  const int tid = threadIdx.x;
  const int wave = tid >> 6, lane = tid & 63;
  const int wm = wave >> 1, wn = wave & 1;     // 2x2 waves: 64 rows x 32 cols/gate
  const int m0 = blockIdx.y * 128;
  const int d0 = blockIdx.x * 64;
  const int lrow = lane >> 2;                              // staged row in chunk
  const int lk = (((lane & 3) ^ ((lrow >> 1) & 3)) * 8);   // staged k offset (halfs)
  const int roff = ((((lane & 15) << 2) | ((lane >> 4) ^ ((lane >> 1) & 3))) * 8); // read offset

  const _Float16* pA0 = xh + (size_t)(m0 + (wave * 2 + 0) * 16 + lrow) * K1 + lk;
  const _Float16* pA1 = pA0 + (size_t)16 * K1;
  const _Float16* pB0 = w1t + (size_t)(d0 + wave * 16 + lrow) * K1 + lk;
  const _Float16* pB1 = pB0 + (size_t)DIN * K1;
  const _Float16* pB2 = pB1 + (size_t)DIN * K1;

  floatx4 acc[3][4][2] = {};

  // prime tiles 0,1
#pragma unroll
  for (int t = 0; t < 2; ++t) {
    gload16(pA0 + t * 32, &As[t][(wave * 2 + 0) * 512]);
    gload16(pA1 + t * 32, &As[t][(wave * 2 + 1) * 512]);
    gload16(pB0 + t * 32, &Bs[t][0][wave * 512]);
    gload16(pB1 + t * 32, &Bs[t][1][wave * 512]);
    gload16(pB2 + t * 32, &Bs[t][2][wave * 512]);
  }
  pA0 += 64; pA1 += 64; pB0 += 64; pB1 += 64; pB2 += 64;

  for (int ito = 0; ito < K1 / 32 / 4; ++ito) {
#pragma unroll
    for (int ii = 0; ii < 4; ++ii) {
      const int sb = (ii + 2) & 3, rb = ii;
      gload16(pA0, &As[sb][(wave * 2 + 0) * 512]);
      gload16(pA1, &As[sb][(wave * 2 + 1) * 512]);
      gload16(pB0, &Bs[sb][0][wave * 512]);
      gload16(pB1, &Bs[sb][1][wave * 512]);
      gload16(pB2, &Bs[sb][2][wave * 512]);
      pA0 += 32; pA1 += 32; pB0 += 32; pB1 += 32; pB2 += 32;

      asm volatile("s_waitcnt vmcnt(10)" ::: "memory");
      __builtin_amdgcn_s_barrier();
      asm volatile("" ::: "memory");

      half8 af[4], bfr[3][2];
#pragma unroll
      for (int mi = 0; mi < 4; ++mi)
        af[mi] = *(const half8*)(&As[rb][(wm * 4 + mi) * 512 + roff]);
#pragma unroll
      for (int gt = 0; gt < 3; ++gt)
#pragma unroll
        for (int ni = 0; ni < 2; ++ni)
          bfr[gt][ni] = *(const half8*)(&Bs[rb][gt][(wn * 2 + ni) * 512 + roff]);
#pragma unroll
      for (int gt = 0; gt < 3; ++gt)
#pragma unroll
        for (int mi = 0; mi < 4; ++mi)
#pragma unroll
          for (int ni = 0; ni < 2; ++ni)
            acc[gt][mi][ni] = __builtin_amdgcn_mfma_f32_16x16x32_f16(
                af[mi], bfr[gt][ni], acc[gt][mi][ni], 0, 0, 0);
    }
  }

  // epilogue: bias + gate math, write packed (z,g)
  // z = sigma(softplus(-f)-softplus(-i)) = u/(u+v), u=1+e^-f, v=1+e^-i
#pragma unroll
  for (int ni = 0; ni < 2; ++ni) {
    int d = d0 + wn * 32 + ni * 16 + (lane & 15);
    float bh = b1[d], bf_ = b1[DIN + d], bi = b1[2 * DIN + d];
#pragma unroll
    for (int mi = 0; mi < 4; ++mi) {
#pragma unroll
      for (int r = 0; r < 4; ++r) {
        int m = m0 + wm * 64 + mi * 16 + (lane >> 4) * 4 + r;
        float hv = acc[0][mi][ni][r] + bh;
        float fv = acc[1][mi][ni][r] + bf_;
        float iv = acc[2][mi][ni][r] + bi;
        float u = 1.f + __expf(-fminf(fmaxf(fv, -30.f), 30.f));
        float v = 1.f + __expf(-fminf(fmaxf(iv, -30.f), 30.f));
        float z = __fdividef(u, u + v);
        float gg = (hv >= 0.f) ? (hv + 0.5f)
                               : __fdividef(1.f, 1.f + __expf(-fmaxf(hv, -30.f)));
        zg[(size_t)m * DIN + d] = hbits(z) | (hbits(gg) << 16);
      }
    }
  }
}

// ---------------- chunked parallel scan: h_t = (1-z) h + z g ----------------

__global__ void scanA(const uint32_t* __restrict__ zg,
                      float* __restrict__ cA, float* __restrict__ cB) {
  int gidx = blockIdx.x * 256 + threadIdx.x;
  int q = gidx >> 13, c = gidx & (NCH - 1);
  int b = c >> 11, d = c & (DIN - 1);
  size_t base = ((size_t)b * SS + q * CLEN) * DIN + d;
  float A = 1.f, Bv = 0.f;
#pragma unroll 4
  for (int t = 0; t < CLEN; ++t) {
    uint32_t v = zg[base + (size_t)t * DIN];
    float z = h_lo(v), g = h_hi(v);
    A *= (1.f - z);
    Bv = fmaf(z, g - Bv, Bv);
  }
  cA[q * NCH + c] = A;
  cB[q * NCH + c] = Bv;
}

__global__ void scanB(const float* __restrict__ cA, const float* __restrict__ cB,
                      const float* __restrict__ init_h, float* __restrict__ cH) {
  int c = blockIdx.x * 256 + threadIdx.x;  // 8192 channels
  int d = c & (DIN - 1);
  float x = init_h[d];
  float h = (x >= 0.f) ? (x + 0.5f) : sigm(x);  // h0 = g(init_h)
#pragma unroll
  for (int q = 0; q < NCHUNK; ++q) {
    cH[q * NCH + c] = h;                        // h at START of chunk q
    h = fmaf(cA[q * NCH + c], h, cB[q * NCH + c]);
  }
}

__global__ void scanC(const uint32_t* __restrict__ zg, const float* __restrict__ cH,
                      _Float16* __restrict__ hh, float* __restrict__ out_tail) {
  int gidx = blockIdx.x * 256 + threadIdx.x;
  int q = gidx >> 13, c = gidx & (NCH - 1);
  int b = c >> 11, d = c & (DIN - 1);
  size_t base = ((size_t)b * SS + q * CLEN) * DIN + d;
  float h = cH[q * NCH + c];
#pragma unroll 4
  for (int t = 0; t < CLEN; ++t) {
    uint32_t v = zg[base + (size_t)t * DIN];
    float z = h_lo(v), g = h_hi(v);
    h = fmaf(z, g - h, h);
    hh[base + (size_t)t * DIN] = (_Float16)h;
  }
  if (q == NCHUNK - 1) {
    out_tail[c] = h;             // next_hidden
    out_tail[NCH + c] = logf(h); // next_log_hidden
  }
}

// ---------------- GEMM2: out_h @ W2 + b2 (128x128, ring-pipelined) ---------
// Natural raster order (see gemm1 comment -- XCD remap regressed FETCH).
__global__ __launch_bounds__(256) void gemm2k(
    const _Float16* __restrict__ hh, const _Float16* __restrict__ w2t,
    const float* __restrict__ b2, float* __restrict__ out) {
  __shared__ _Float16 As[4][128 * 32];   // 4 x 8KB
  __shared__ _Float16 Bs[4][128 * 32];   // 4 x 8KB ; 64KB total

  const int tid = threadIdx.x;
  const int wave = tid >> 6, lane = tid & 63;
  const int wm = wave >> 1, wn = wave & 1;     // 2x2 waves: 64x64 each
  const int m0 = blockIdx.y * 128;
  const int n0 = blockIdx.x * 128;
  const int lrow = lane >> 2;
  const int lk = (((lane & 3) ^ ((lrow >> 1) & 3)) * 8);   // conflict-free swz (see gemm1)
  const int roff = ((((lane & 15) << 2) | ((lane >> 4) ^ ((lane >> 1) & 3))) * 8);

  const _Float16* pA0 = hh + (size_t)(m0 + (wave * 2 + 0) * 16 + lrow) * K2 + lk;
  const _Float16* pA1 = pA0 + (size_t)16 * K2;
  const _Float16* pB0 = w2t + (size_t)(n0 + (wave * 2 + 0) * 16 + lrow) * K2 + lk;
  const _Float16* pB1 = pB0 + (size_t)16 * K2;

  floatx4 acc[4][4] = {};

#pragma unroll
  for (int t = 0; t < 2; ++t) {
    gload16(pA0 + t * 32, &As[t][(wave * 2 + 0) * 512]);
    gload16(pA1 + t * 32, &As[t][(wave * 2 + 1) * 512]);
    gload16(pB0 + t * 32, &Bs[t][(wave * 2 + 0) * 512]);
    gload16(pB1 + t * 32, &Bs[t][(wave * 2 + 1) * 512]);
  }
  pA0 += 64; pA1 += 64; pB0 += 64; pB1 += 64;

  for (int ito = 0; ito < K2 / 32 / 4; ++ito) {
#pragma unroll
    for (int ii = 0; ii < 4; ++ii) {
      const int sb = (ii + 2) & 3, rb = ii;
      gload16(pA0, &As[sb][(wave * 2 + 0) * 512]);
      gload16(pA1, &As[sb][(wave * 2 + 1) * 512]);
      gload16(pB0, &Bs[sb][(wave * 2 + 0) * 512]);
      gload16(pB1, &Bs[sb][(wave * 2 + 1) * 512]);
      pA0 += 32; pA1 += 32; pB0 += 32; pB1 += 32;

      asm volatile("s_waitcnt vmcnt(8)" ::: "memory");
      __builtin_amdgcn_s_barrier();
      asm volatile("" ::: "memory");

      half8 af[4], bfr[4];
#pragma unroll
      for (int mi = 0; mi < 4; ++mi)
        af[mi] = *(const half8*)(&As[rb][(wm * 4 + mi) * 512 + roff]);
#pragma unroll
      for (int ni = 0; ni < 4; ++ni)
        bfr[ni] = *(const half8*)(&Bs[rb][(wn * 4 + ni) * 512 + roff]);
#pragma unroll
      for (int mi = 0; mi < 4; ++mi)
#pragma unroll
        for (int ni = 0; ni < 4; ++ni)
          acc[mi][ni] = __builtin_amdgcn_mfma_f32_16x16x32_f16(af[mi], bfr[ni], acc[mi][ni], 0, 0, 0);
    }
  }

#pragma unroll
  for (int ni = 0; ni < 4; ++ni) {
    int n = n0 + wn * 64 + ni * 16 + (lane & 15);
    float bias = b2[n];
#pragma unroll
    for (int mi = 0; mi < 4; ++mi) {
#pragma unroll
      for (int r = 0; r < 4; ++r) {
        int m = m0 + wm * 64 + mi * 16 + (lane >> 4) * 4 + r;
        out[(size_t)m * N2 + n] = acc[mi][ni][r] + bias;
      }
    }
  }
}

// ---------------- launch ----------------

extern "C" void kernel_launch(void* const* d_in, const int* in_sizes, int n_in,
                              void* d_out, int out_size, void* d_ws, size_t ws_size,
                              hipStream_t stream) {
  const float* x      = (const float*)d_in[0];
  const float* W1     = (const float*)d_in[1];
  const float* b1     = (const float*)d_in[2];
  const float* W2     = (const float*)d_in[3];
  const float* b2     = (const float*)d_in[4];
  const float* init_h = (const float*)d_in[5];
  float* out = (float*)d_out;

  char* w = (char*)d_ws;
  _Float16* xh  = (_Float16*)w; w += (size_t)MTOT * K1 * 2;       // 32 MB
  _Float16* w1t = (_Float16*)w; w += (size_t)3 * DIN * K1 * 2;    // 12 MB
  _Float16* w2t = (_Float16*)w; w += (size_t)N2 * K2 * 2;         // 4 MB
  uint32_t* zg  = (uint32_t*)w; w += (size_t)MTOT * DIN * 4;      // 128 MB
  _Float16* hh  = (_Float16*)w; w += (size_t)MTOT * DIN * 2;      // 64 MB
  float* cA = (float*)w; w += (size_t)NCH * NCHUNK * 4;
  float* cB = (float*)w; w += (size_t)NCH * NCHUNK * 4;
  float* cH = (float*)w; w += (size_t)NCH * NCHUNK * 4;

  f32_to_f16_vec<<<dim3(MTOT * K1 / 1024), dim3(256), 0, stream>>>(x, xh);
  transpose_cvt<<<dim3(3 * DIN / 32, K1 / 32), dim3(32, 8), 0, stream>>>(W1, w1t, K1, 3 * DIN);
  transpose_cvt<<<dim3(N2 / 32, K2 / 32), dim3(32, 8), 0, stream>>>(W2, w2t, K2, N2);

  gemm1_fused<<<dim3(DIN / 64, MTOT / 128), dim3(256), 0, stream>>>(xh, w1t, b1, zg);

  scanA<<<dim3(NCH * NCHUNK / 256), dim3(256), 0, stream>>>(zg, cA, cB);
  scanB<<<dim3(NCH / 256), dim3(256), 0, stream>>>(cA, cB, init_h, cH);
  scanC<<<dim3(NCH * NCHUNK / 256), dim3(256), 0, stream>>>(zg, cH, hh, out + (size_t)MTOT * DD);

  gemm2k<<<dim3(N2 / 128, MTOT / 128), dim3(256), 0, stream>>>(hh, w2t, b2, out);
}

// Round 4
// 548.516 us; speedup vs baseline: 1.1625x; 1.0521x over previous
//
#include <hip/hip_runtime.h>
#include <cstdint>
#include <cstddef>

// Problem constants (B=4, S=4096, D=1024, Din=2048)
#define BB 4
#define SS 4096
#define DD 1024
#define DIN 2048
#define MTOT (BB*SS)        // 16384 rows
#define K1 DD               // GEMM1 K = 1024
#define K2 DIN              // GEMM2 K = 2048
#define N2 DD               // GEMM2 N = 1024
#define NCH (BB*DIN)        // 8192 scan channels
#define NCHUNK 32
#define CLEN (SS/NCHUNK)    // 128

typedef _Float16 half8  __attribute__((ext_vector_type(8)));
typedef _Float16 half4v __attribute__((ext_vector_type(4)));
typedef float    floatx4 __attribute__((ext_vector_type(4)));

#define AS1(p) ((__attribute__((address_space(1))) void*)(uintptr_t)(p))
#define AS3(p) ((__attribute__((address_space(3))) void*)(uint32_t)(uintptr_t)(p))

__device__ __forceinline__ void gload16(const void* g, void* l) {
  // async global->LDS, 16B/lane; LDS dest = wave-uniform base + lane*16
  __builtin_amdgcn_global_load_lds(AS1(g), AS3(l), 16, 0, 0);
}

__device__ __forceinline__ float sigm(float x) { return 1.f / (1.f + __expf(-x)); }
__device__ __forceinline__ uint32_t hbits(float f) {
  _Float16 h = (_Float16)f; uint16_t u; __builtin_memcpy(&u, &h, 2); return (uint32_t)u;
}
__device__ __forceinline__ float h_lo(uint32_t v) {
  uint16_t u = (uint16_t)(v & 0xffffu); _Float16 h; __builtin_memcpy(&h, &u, 2); return (float)h;
}
__device__ __forceinline__ float h_hi(uint32_t v) {
  uint16_t u = (uint16_t)(v >> 16); _Float16 h; __builtin_memcpy(&h, &u, 2); return (float)h;
}

// ---------------- elementwise converts ----------------

__global__ void f32_to_f16_vec(const float* __restrict__ src, _Float16* __restrict__ dst) {
  int i = (blockIdx.x * blockDim.x + threadIdx.x) * 4;
  float4 v = *(const float4*)(src + i);
  half4v o; o.x = (_Float16)v.x; o.y = (_Float16)v.y; o.z = (_Float16)v.z; o.w = (_Float16)v.w;
  *(half4v*)(dst + i) = o;
}

// src[R][C] f32 -> dst[C][R] f16
__global__ void transpose_cvt(const float* __restrict__ src, _Float16* __restrict__ dst,
                              int R, int C) {
  __shared__ float t[32][33];
  int c0 = blockIdx.x * 32, r0 = blockIdx.y * 32;
  int tx = threadIdx.x, ty = threadIdx.y;
#pragma unroll
  for (int j = 0; j < 32; j += 8)
    t[ty + j][tx] = src[(size_t)(r0 + ty + j) * C + c0 + tx];
  __syncthreads();
#pragma unroll
  for (int j = 0; j < 32; j += 8)
    dst[(size_t)(c0 + ty + j) * R + r0 + tx] = (_Float16)t[tx][ty + j];
}

// ---------------- GEMM1: x @ W1 fused with gate math ----------------
// Ring-3 LDS (60KB -> 2 blocks/CU; the old ring-4 80KB exact-fit failed and
// ran 1 block/CU, Occupancy 11.5% -- measured r3), counted vmcnt (never 0).
// K-step: [vmcnt(5): tile t done, t+1 in flight] [barrier] [stage t+2]
// [ds_read t] [MFMA]. WAR-safe: stage(t+2) writes buf (t-1)%3 whose readers
// all passed this iteration's barrier (their lgkm waits precede their MFMAs).
// Prefetch distance stays 2 K-steps > HBM latency. Tail iters issue dummy
// loads a few hundred B past the tensor into the adjacent ws buffer.
//
// LDS swizzle: per-row k-group XOR swz(r) = (r>>1)&3 (applied to the GLOBAL
// source address; gload_lds dest stays linear). Read slot = 4r + (q^swz(r))
// -> bank-set covers all 8 sets 2x per 16-lane quarter = conflict-free b128
// (measured r2: SQ_LDS_BANK_CONFLICT = 0).
//
// Block order: NATURAL raster (bx fast). Measured r2: XCD-chunked remap
// tripled HBM FETCH (234->808 MB). Do not re-introduce block swizzles here
// without watching FETCH_SIZE.
__global__ __launch_bounds__(256) void gemm1_fused(
    const _Float16* __restrict__ xh, const _Float16* __restrict__ w1t,
    const float* __restrict__ b1, uint32_t* __restrict__ zg) {
  __shared__ _Float16 As[3][128 * 32];      // 3 x 8KB
  __shared__ _Float16 Bs[3][3][64 * 32];    // 3 x 12KB ; 60KB total

  const int tid = threadIdx.x;
  const int wave = tid >> 6, lane = tid & 63;
  const int wm = wave >> 1, wn = wave & 1;     // 2x2 waves: 64 rows x 32 cols/gate
  const int m0 = blockIdx.y * 128;
  const int d0 = blockIdx.x * 64;
  const int lrow = lane >> 2;                              // staged row in chunk
  const int lk = (((lane & 3) ^ ((lrow >> 1) & 3)) * 8);   // staged k offset (halfs)
  const int roff = ((((lane & 15) << 2) | ((lane >> 4) ^ ((lane >> 1) & 3))) * 8); // read offset

  const _Float16* pA0 = xh + (size_t)(m0 + (wave * 2 + 0) * 16 + lrow) * K1 + lk;
  const _Float16* pA1 = pA0 + (size_t)16 * K1;
  const _Float16* pB0 = w1t + (size_t)(d0 + wave * 16 + lrow) * K1 + lk;
  const _Float16* pB1 = pB0 + (size_t)DIN * K1;
  const _Float16* pB2 = pB1 + (size_t)DIN * K1;

  floatx4 acc[3][4][2] = {};

  // prime tiles 0,1 into bufs 0,1
#pragma unroll
  for (int t = 0; t < 2; ++t) {
    gload16(pA0 + t * 32, &As[t][(wave * 2 + 0) * 512]);
    gload16(pA1 + t * 32, &As[t][(wave * 2 + 1) * 512]);
    gload16(pB0 + t * 32, &Bs[t][0][wave * 512]);
    gload16(pB1 + t * 32, &Bs[t][1][wave * 512]);
    gload16(pB2 + t * 32, &Bs[t][2][wave * 512]);
  }
  pA0 += 64; pA1 += 64; pB0 += 64; pB1 += 64; pB2 += 64;

#define G1_STEP(rb, sb)                                                         \
  do {                                                                          \
    asm volatile("s_waitcnt vmcnt(5)" ::: "memory");                            \
    __builtin_amdgcn_s_barrier();                                               \
    asm volatile("" ::: "memory");                                              \
    gload16(pA0, &As[sb][(wave * 2 + 0) * 512]);                                \
    gload16(pA1, &As[sb][(wave * 2 + 1) * 512]);                                \
    gload16(pB0, &Bs[sb][0][wave * 512]);                                       \
    gload16(pB1, &Bs[sb][1][wave * 512]);                                       \
    gload16(pB2, &Bs[sb][2][wave * 512]);                                       \
    pA0 += 32; pA1 += 32; pB0 += 32; pB1 += 32; pB2 += 32;                      \
    half8 af[4], bfr[3][2];                                                     \
    _Pragma("unroll")                                                           \
    for (int mi = 0; mi < 4; ++mi)                                              \
      af[mi] = *(const half8*)(&As[rb][(wm * 4 + mi) * 512 + roff]);            \
    _Pragma("unroll")                                                           \
    for (int gt = 0; gt < 3; ++gt)                                              \
      _Pragma("unroll")                                                         \
      for (int ni = 0; ni < 2; ++ni)                                            \
        bfr[gt][ni] = *(const half8*)(&Bs[rb][gt][(wn * 2 + ni) * 512 + roff]); \
    _Pragma("unroll")                                                           \
    for (int gt = 0; gt < 3; ++gt)                                              \
      _Pragma("unroll")                                                         \
      for (int mi = 0; mi < 4; ++mi)                                            \
        _Pragma("unroll")                                                       \
        for (int ni = 0; ni < 2; ++ni)                                          \
          acc[gt][mi][ni] = __builtin_amdgcn_mfma_f32_16x16x32_f16(             \
              af[mi], bfr[gt][ni], acc[gt][mi][ni], 0, 0, 0);                   \
  } while (0)

  // 32 K-tiles = 10 x 3 + 2; tile k reads buf k%3, stages tile k+2 -> (k+2)%3
  for (int it3 = 0; it3 < 10; ++it3) {
    G1_STEP(0, 2); G1_STEP(1, 0); G1_STEP(2, 1);
  }
  G1_STEP(0, 2); G1_STEP(1, 0);
#undef G1_STEP

  // epilogue: bias + gate math, write packed (z,g)
  // z = sigma(softplus(-f)-softplus(-i)) = u/(u+v), u=1+e^-f, v=1+e^-i
#pragma unroll
  for (int ni = 0; ni < 2; ++ni) {
    int d = d0 + wn * 32 + ni * 16 + (lane & 15);
    float bh = b1[d], bf_ = b1[DIN + d], bi = b1[2 * DIN + d];
#pragma unroll
    for (int mi = 0; mi < 4; ++mi) {
#pragma unroll
      for (int r = 0; r < 4; ++r) {
        int m = m0 + wm * 64 + mi * 16 + (lane >> 4) * 4 + r;
        float hv = acc[0][mi][ni][r] + bh;
        float fv = acc[1][mi][ni][r] + bf_;
        float iv = acc[2][mi][ni][r] + bi;
        float u = 1.f + __expf(-fminf(fmaxf(fv, -30.f), 30.f));
        float v = 1.f + __expf(-fminf(fmaxf(iv, -30.f), 30.f));
        float z = __fdividef(u, u + v);
        float gg = (hv >= 0.f) ? (hv + 0.5f)
                               : __fdividef(1.f, 1.f + __expf(-fmaxf(hv, -30.f)));
        zg[(size_t)m * DIN + d] = hbits(z) | (hbits(gg) << 16);
      }
    }
  }
}

// ---------------- chunked parallel scan: h_t = (1-z) h + z g ----------------

__global__ void scanA(const uint32_t* __restrict__ zg,
                      float* __restrict__ cA, float* __restrict__ cB) {
  int gidx = blockIdx.x * 256 + threadIdx.x;
  int q = gidx >> 13, c = gidx & (NCH - 1);
  int b = c >> 11, d = c & (DIN - 1);
  size_t base = ((size_t)b * SS + q * CLEN) * DIN + d;
  float A = 1.f, Bv = 0.f;
#pragma unroll 4
  for (int t = 0; t < CLEN; ++t) {
    uint32_t v = zg[base + (size_t)t * DIN];
    float z = h_lo(v), g = h_hi(v);
    A *= (1.f - z);
    Bv = fmaf(z, g - Bv, Bv);
  }
  cA[q * NCH + c] = A;
  cB[q * NCH + c] = Bv;
}

__global__ void scanB(const float* __restrict__ cA, const float* __restrict__ cB,
                      const float* __restrict__ init_h, float* __restrict__ cH) {
  int c = blockIdx.x * 256 + threadIdx.x;  // 8192 channels
  int d = c & (DIN - 1);
  float x = init_h[d];
  float h = (x >= 0.f) ? (x + 0.5f) : sigm(x);  // h0 = g(init_h)
#pragma unroll
  for (int q = 0; q < NCHUNK; ++q) {
    cH[q * NCH + c] = h;                        // h at START of chunk q
    h = fmaf(cA[q * NCH + c], h, cB[q * NCH + c]);
  }
}

__global__ void scanC(const uint32_t* __restrict__ zg, const float* __restrict__ cH,
                      _Float16* __restrict__ hh, float* __restrict__ out_tail) {
  int gidx = blockIdx.x * 256 + threadIdx.x;
  int q = gidx >> 13, c = gidx & (NCH - 1);
  int b = c >> 11, d = c & (DIN - 1);
  size_t base = ((size_t)b * SS + q * CLEN) * DIN + d;
  float h = cH[q * NCH + c];
#pragma unroll 4
  for (int t = 0; t < CLEN; ++t) {
    uint32_t v = zg[base + (size_t)t * DIN];
    float z = h_lo(v), g = h_hi(v);
    h = fmaf(z, g - h, h);
    hh[base + (size_t)t * DIN] = (_Float16)h;
  }
  if (q == NCHUNK - 1) {
    out_tail[c] = h;             // next_hidden
    out_tail[NCH + c] = logf(h); // next_log_hidden
  }
}

// ---------------- GEMM2: out_h @ W2 + b2 (128x128, ring-3 pipelined) -------
// Same ring-3 structure as gemm1: 48KB LDS -> 3 blocks/CU. vmcnt(4) = wait
// tile t (4 loads), tile t+1 stays in flight. Natural raster order.
__global__ __launch_bounds__(256) void gemm2k(
    const _Float16* __restrict__ hh, const _Float16* __restrict__ w2t,
    const float* __restrict__ b2, float* __restrict__ out) {
  __shared__ _Float16 As[3][128 * 32];   // 3 x 8KB
  __shared__ _Float16 Bs[3][128 * 32];   // 3 x 8KB ; 48KB total

  const int tid = threadIdx.x;
  const int wave = tid >> 6, lane = tid & 63;
  const int wm = wave >> 1, wn = wave & 1;     // 2x2 waves: 64x64 each
  const int m0 = blockIdx.y * 128;
  const int n0 = blockIdx.x * 128;
  const int lrow = lane >> 2;
  const int lk = (((lane & 3) ^ ((lrow >> 1) & 3)) * 8);   // conflict-free swz (see gemm1)
  const int roff = ((((lane & 15) << 2) | ((lane >> 4) ^ ((lane >> 1) & 3))) * 8);

  const _Float16* pA0 = hh + (size_t)(m0 + (wave * 2 + 0) * 16 + lrow) * K2 + lk;
  const _Float16* pA1 = pA0 + (size_t)16 * K2;
  const _Float16* pB0 = w2t + (size_t)(n0 + (wave * 2 + 0) * 16 + lrow) * K2 + lk;
  const _Float16* pB1 = pB0 + (size_t)16 * K2;

  floatx4 acc[4][4] = {};

  // prime tiles 0,1 into bufs 0,1
#pragma unroll
  for (int t = 0; t < 2; ++t) {
    gload16(pA0 + t * 32, &As[t][(wave * 2 + 0) * 512]);
    gload16(pA1 + t * 32, &As[t][(wave * 2 + 1) * 512]);
    gload16(pB0 + t * 32, &Bs[t][(wave * 2 + 0) * 512]);
    gload16(pB1 + t * 32, &Bs[t][(wave * 2 + 1) * 512]);
  }
  pA0 += 64; pA1 += 64; pB0 += 64; pB1 += 64;

#define G2_STEP(rb, sb)                                                         \
  do {                                                                          \
    asm volatile("s_waitcnt vmcnt(4)" ::: "memory");                            \
    __builtin_amdgcn_s_barrier();                                               \
    asm volatile("" ::: "memory");                                              \
    gload16(pA0, &As[sb][(wave * 2 + 0) * 512]);                                \
    gload16(pA1, &As[sb][(wave * 2 + 1) * 512]);                                \
    gload16(pB0, &Bs[sb][(wave * 2 + 0) * 512]);                                \
    gload16(pB1, &Bs[sb][(wave * 2 + 1) * 512]);                                \
    pA0 += 32; pA1 += 32; pB0 += 32; pB1 += 32;                                 \
    half8 af[4], bfr[4];                                                        \
    _Pragma("unroll")                                                           \
    for (int mi = 0; mi < 4; ++mi)                                              \
      af[mi] = *(const half8*)(&As[rb][(wm * 4 + mi) * 512 + roff]);            \
    _Pragma("unroll")                                                           \
    for (int ni = 0; ni < 4; ++ni)                                              \
      bfr[ni] = *(const half8*)(&Bs[rb][(wn * 4 + ni) * 512 + roff]);           \
    _Pragma("unroll")                                                           \
    for (int mi = 0; mi < 4; ++mi)                                              \
      _Pragma("unroll")                                                         \
      for (int ni = 0; ni < 4; ++ni)                                            \
        acc[mi][ni] = __builtin_amdgcn_mfma_f32_16x16x32_f16(                   \
            af[mi], bfr[ni], acc[mi][ni], 0, 0, 0);                             \
  } while (0)

  // 64 K-tiles = 21 x 3 + 1
  for (int it3 = 0; it3 < 21; ++it3) {
    G2_STEP(0, 2); G2_STEP(1, 0); G2_STEP(2, 1);
  }
  G2_STEP(0, 2);
#undef G2_STEP

#pragma unroll
  for (int ni = 0; ni < 4; ++ni) {
    int n = n0 + wn * 64 + ni * 16 + (lane & 15);
    float bias = b2[n];
#pragma unroll
    for (int mi = 0; mi < 4; ++mi) {
#pragma unroll
      for (int r = 0; r < 4; ++r) {
        int m = m0 + wm * 64 + mi * 16 + (lane >> 4) * 4 + r;
        out[(size_t)m * N2 + n] = acc[mi][ni][r] + bias;
      }
    }
  }
}

// ---------------- launch ----------------

extern "C" void kernel_launch(void* const* d_in, const int* in_sizes, int n_in,
                              void* d_out, int out_size, void* d_ws, size_t ws_size,
                              hipStream_t stream) {
  const float* x      = (const float*)d_in[0];
  const float* W1     = (const float*)d_in[1];
  const float* b1     = (const float*)d_in[2];
  const float* W2     = (const float*)d_in[3];
  const float* b2     = (const float*)d_in[4];
  const float* init_h = (const float*)d_in[5];
  float* out = (float*)d_out;

  char* w = (char*)d_ws;
  _Float16* xh  = (_Float16*)w; w += (size_t)MTOT * K1 * 2;       // 32 MB
  _Float16* w1t = (_Float16*)w; w += (size_t)3 * DIN * K1 * 2;    // 12 MB
  _Float16* w2t = (_Float16*)w; w += (size_t)N2 * K2 * 2;         // 4 MB
  uint32_t* zg  = (uint32_t*)w; w += (size_t)MTOT * DIN * 4;      // 128 MB
  _Float16* hh  = (_Float16*)w; w += (size_t)MTOT * DIN * 2;      // 64 MB
  float* cA = (float*)w; w += (size_t)NCH * NCHUNK * 4;
  float* cB = (float*)w; w += (size_t)NCH * NCHUNK * 4;
  float* cH = (float*)w; w += (size_t)NCH * NCHUNK * 4;

  f32_to_f16_vec<<<dim3(MTOT * K1 / 1024), dim3(256), 0, stream>>>(x, xh);
  transpose_cvt<<<dim3(3 * DIN / 32, K1 / 32), dim3(32, 8), 0, stream>>>(W1, w1t, K1, 3 * DIN);
  transpose_cvt<<<dim3(N2 / 32, K2 / 32), dim3(32, 8), 0, stream>>>(W2, w2t, K2, N2);

  gemm1_fused<<<dim3(DIN / 64, MTOT / 128), dim3(256), 0, stream>>>(xh, w1t, b1, zg);

  scanA<<<dim3(NCH * NCHUNK / 256), dim3(256), 0, stream>>>(zg, cA, cB);
  scanB<<<dim3(NCH / 256), dim3(256), 0, stream>>>(cA, cB, init_h, cH);
  scanC<<<dim3(NCH * NCHUNK / 256), dim3(256), 0, stream>>>(zg, cH, hh, out + (size_t)MTOT * DD);

  gemm2k<<<dim3(N2 / 128, MTOT / 128), dim3(256), 0, stream>>>(hh, w2t, b2, out);
}

// Round 5
// 542.094 us; speedup vs baseline: 1.1763x; 1.0118x over previous
//
#include <hip/hip_runtime.h>
#include <cstdint>
#include <cstddef>

// Problem constants (B=4, S=4096, D=1024, Din=2048)
#define BB 4
#define SS 4096
#define DD 1024
#define DIN 2048
#define MTOT (BB*SS)        // 16384 rows
#define K1 DD               // GEMM1 K = 1024
#define K2 DIN              // GEMM2 K = 2048
#define N2 DD               // GEMM2 N = 1024
#define NCH (BB*DIN)        // 8192 scan channels
#define NCHUNK 32
#define CLEN (SS/NCHUNK)    // 128

typedef _Float16 half8  __attribute__((ext_vector_type(8)));
typedef _Float16 half4v __attribute__((ext_vector_type(4)));
typedef float    floatx4 __attribute__((ext_vector_type(4)));

#define AS1(p) ((__attribute__((address_space(1))) void*)(uintptr_t)(p))
#define AS3(p) ((__attribute__((address_space(3))) void*)(uint32_t)(uintptr_t)(p))

__device__ __forceinline__ void gload16(const void* g, void* l) {
  // async global->LDS, 16B/lane; LDS dest = wave-uniform base + lane*16
  __builtin_amdgcn_global_load_lds(AS1(g), AS3(l), 16, 0, 0);
}

__device__ __forceinline__ float sigm(float x) { return 1.f / (1.f + __expf(-x)); }
__device__ __forceinline__ uint32_t hbits(float f) {
  _Float16 h = (_Float16)f; uint16_t u; __builtin_memcpy(&u, &h, 2); return (uint32_t)u;
}
__device__ __forceinline__ float h_lo(uint32_t v) {
  uint16_t u = (uint16_t)(v & 0xffffu); _Float16 h; __builtin_memcpy(&h, &u, 2); return (float)h;
}
__device__ __forceinline__ float h_hi(uint32_t v) {
  uint16_t u = (uint16_t)(v >> 16); _Float16 h; __builtin_memcpy(&h, &u, 2); return (float)h;
}

// ---------------- elementwise converts ----------------

__global__ void f32_to_f16_vec(const float* __restrict__ src, _Float16* __restrict__ dst) {
  int i = (blockIdx.x * blockDim.x + threadIdx.x) * 4;
  float4 v = *(const float4*)(src + i);
  half4v o; o.x = (_Float16)v.x; o.y = (_Float16)v.y; o.z = (_Float16)v.z; o.w = (_Float16)v.w;
  *(half4v*)(dst + i) = o;
}

// src[R][C] f32 -> dst[C][R] f16
__global__ void transpose_cvt(const float* __restrict__ src, _Float16* __restrict__ dst,
                              int R, int C) {
  __shared__ float t[32][33];
  int c0 = blockIdx.x * 32, r0 = blockIdx.y * 32;
  int tx = threadIdx.x, ty = threadIdx.y;
#pragma unroll
  for (int j = 0; j < 32; j += 8)
    t[ty + j][tx] = src[(size_t)(r0 + ty + j) * C + c0 + tx];
  __syncthreads();
#pragma unroll
  for (int j = 0; j < 32; j += 8)
    dst[(size_t)(c0 + ty + j) * R + r0 + tx] = (_Float16)t[tx][ty + j];
}

// ---------------- GEMM1: x @ W1 fused with gate math ----------------
// Asymmetric ring, 48KB total -> 3 blocks/CU (r4's 60KB ring-3 gave 2/CU,
// Occupancy 22%; r3's 80KB gave 1/CU -- occupancy is the measured lever).
//   A: ring-3 (3 x 8KB), prefetch distance 2  (xh streams from HBM)
//   B: ring-2 (2 x 12KB), prefetch distance 1 (w1t is 12MB, swept in-phase
//      by all co-resident blocks -> L2/L3-hot, 1-step lead suffices)
// Per step t: [wait vmcnt(2)] [barrier] [stage B(t+1), then A(t+2)]
// [ds_read tile t] [MFMA]. Issue order makes A(t+2) the youngest 2 loads:
// vmcnt(2) forces A(t), B(t) (and older) complete, leaves A(t+2) in flight.
// WAR-safe: stage targets hold tile t-1 whose readers all passed this
// step's barrier (their lgkm waits precede their step-(t-1) MFMAs).
// RAW-safe: wait precedes barrier, so after barrier ALL waves' tile-t
// loads are complete. Tail steps issue dummy loads a few hundred B past
// the tensor into the adjacent ws buffer (branch-free, constant vmcnt).
//
// LDS swizzle: per-row k-group XOR swz(r) = (r>>1)&3 (applied to the GLOBAL
// source address; gload_lds dest stays linear). Conflict-free b128 reads
// (measured r2: SQ_LDS_BANK_CONFLICT = 0).
//
// Block order: NATURAL raster (bx fast). Measured r2: XCD-chunked remap
// tripled HBM FETCH (234->808 MB). Do not re-introduce block swizzles here
// without watching FETCH_SIZE.
__global__ __launch_bounds__(256) void gemm1_fused(
    const _Float16* __restrict__ xh, const _Float16* __restrict__ w1t,
    const float* __restrict__ b1, uint32_t* __restrict__ zg) {
  __shared__ _Float16 As[3][128 * 32];      // 3 x 8KB  = 24KB
  __shared__ _Float16 Bs[2][3][64 * 32];    // 2 x 12KB = 24KB ; 48KB total

  const int tid = threadIdx.x;
  const int wave = tid >> 6, lane = tid & 63;
  const int wm = wave >> 1, wn = wave & 1;     // 2x2 waves: 64 rows x 32 cols/gate
  const int m0 = blockIdx.y * 128;
  const int d0 = blockIdx.x * 64;
  const int lrow = lane >> 2;                              // staged row in chunk
  const int lk = (((lane & 3) ^ ((lrow >> 1) & 3)) * 8);   // staged k offset (halfs)
  const int roff = ((((lane & 15) << 2) | ((lane >> 4) ^ ((lane >> 1) & 3))) * 8); // read offset

  const _Float16* pA0 = xh + (size_t)(m0 + (wave * 2 + 0) * 16 + lrow) * K1 + lk;
  const _Float16* pA1 = pA0 + (size_t)16 * K1;
  const _Float16* pB0 = w1t + (size_t)(d0 + wave * 16 + lrow) * K1 + lk;
  const _Float16* pB1 = pB0 + (size_t)DIN * K1;
  const _Float16* pB2 = pB1 + (size_t)DIN * K1;

  floatx4 acc[3][4][2] = {};

  // prologue: issue order B(0) x3, A(0) x2, A(1) x2  (7 outstanding)
  gload16(pB0, &Bs[0][0][wave * 512]);
  gload16(pB1, &Bs[0][1][wave * 512]);
  gload16(pB2, &Bs[0][2][wave * 512]);
  gload16(pA0, &As[0][(wave * 2 + 0) * 512]);
  gload16(pA1, &As[0][(wave * 2 + 1) * 512]);
  gload16(pA0 + 32, &As[1][(wave * 2 + 0) * 512]);
  gload16(pA1 + 32, &As[1][(wave * 2 + 1) * 512]);
  pB0 += 32; pB1 += 32; pB2 += 32;   // -> tile 1
  pA0 += 64; pA1 += 64;              // -> tile 2

#define G1_STEP(rbA, sbA, rbB, sbB)                                             \
  do {                                                                          \
    asm volatile("s_waitcnt vmcnt(2)" ::: "memory");                            \
    __builtin_amdgcn_s_barrier();                                               \
    asm volatile("" ::: "memory");                                              \
    gload16(pB0, &Bs[sbB][0][wave * 512]);                                      \
    gload16(pB1, &Bs[sbB][1][wave * 512]);                                      \
    gload16(pB2, &Bs[sbB][2][wave * 512]);                                      \
    gload16(pA0, &As[sbA][(wave * 2 + 0) * 512]);                               \
    gload16(pA1, &As[sbA][(wave * 2 + 1) * 512]);                               \
    pA0 += 32; pA1 += 32; pB0 += 32; pB1 += 32; pB2 += 32;                      \
    half8 af[4], bfr[3][2];                                                     \
    _Pragma("unroll")                                                           \
    for (int mi = 0; mi < 4; ++mi)                                              \
      af[mi] = *(const half8*)(&As[rbA][(wm * 4 + mi) * 512 + roff]);           \
    _Pragma("unroll")                                                           \
    for (int gt = 0; gt < 3; ++gt)                                              \
      _Pragma("unroll")                                                         \
      for (int ni = 0; ni < 2; ++ni)                                            \
        bfr[gt][ni] = *(const half8*)(&Bs[rbB][gt][(wn * 2 + ni) * 512 + roff]);\
    _Pragma("unroll")                                                           \
    for (int gt = 0; gt < 3; ++gt)                                              \
      _Pragma("unroll")                                                         \
      for (int mi = 0; mi < 4; ++mi)                                            \
        _Pragma("unroll")                                                       \
        for (int ni = 0; ni < 2; ++ni)                                          \
          acc[gt][mi][ni] = __builtin_amdgcn_mfma_f32_16x16x32_f16(             \
              af[mi], bfr[gt][ni], acc[gt][mi][ni], 0, 0, 0);                   \
  } while (0)

  // 32 K-tiles; tile t reads As[t%3], Bs[t&1]; stages A(t+2)->(t+2)%3,
  // B(t+1)->(t+1)&1. Pattern period lcm(3,2)=6; 32 = 5*6 + 2.
  for (int it6 = 0; it6 < 5; ++it6) {
    G1_STEP(0, 2, 0, 1);
    G1_STEP(1, 0, 1, 0);
    G1_STEP(2, 1, 0, 1);
    G1_STEP(0, 2, 1, 0);
    G1_STEP(1, 0, 0, 1);
    G1_STEP(2, 1, 1, 0);
  }
  G1_STEP(0, 2, 0, 1);   // t=30
  G1_STEP(1, 0, 1, 0);   // t=31
#undef G1_STEP

  // epilogue: bias + gate math, write packed (z,g)
  // z = sigma(softplus(-f)-softplus(-i)) = u/(u+v), u=1+e^-f, v=1+e^-i
#pragma unroll
  for (int ni = 0; ni < 2; ++ni) {
    int d = d0 + wn * 32 + ni * 16 + (lane & 15);
    float bh = b1[d], bf_ = b1[DIN + d], bi = b1[2 * DIN + d];
#pragma unroll
    for (int mi = 0; mi < 4; ++mi) {
#pragma unroll
      for (int r = 0; r < 4; ++r) {
        int m = m0 + wm * 64 + mi * 16 + (lane >> 4) * 4 + r;
        float hv = acc[0][mi][ni][r] + bh;
        float fv = acc[1][mi][ni][r] + bf_;
        float iv = acc[2][mi][ni][r] + bi;
        float u = 1.f + __expf(-fminf(fmaxf(fv, -30.f), 30.f));
        float v = 1.f + __expf(-fminf(fmaxf(iv, -30.f), 30.f));
        float z = __fdividef(u, u + v);
        float gg = (hv >= 0.f) ? (hv + 0.5f)
                               : __fdividef(1.f, 1.f + __expf(-fmaxf(hv, -30.f)));
        zg[(size_t)m * DIN + d] = hbits(z) | (hbits(gg) << 16);
      }
    }
  }
}

// ---------------- chunked parallel scan: h_t = (1-z) h + z g ----------------

__global__ void scanA(const uint32_t* __restrict__ zg,
                      float* __restrict__ cA, float* __restrict__ cB) {
  int gidx = blockIdx.x * 256 + threadIdx.x;
  int q = gidx >> 13, c = gidx & (NCH - 1);
  int b = c >> 11, d = c & (DIN - 1);
  size_t base = ((size_t)b * SS + q * CLEN) * DIN + d;
  float A = 1.f, Bv = 0.f;
#pragma unroll 4
  for (int t = 0; t < CLEN; ++t) {
    uint32_t v = zg[base + (size_t)t * DIN];
    float z = h_lo(v), g = h_hi(v);
    A *= (1.f - z);
    Bv = fmaf(z, g - Bv, Bv);
  }
  cA[q * NCH + c] = A;
  cB[q * NCH + c] = Bv;
}

__global__ void scanB(const float* __restrict__ cA, const float* __restrict__ cB,
                      const float* __restrict__ init_h, float* __restrict__ cH) {
  int c = blockIdx.x * 256 + threadIdx.x;  // 8192 channels
  int d = c & (DIN - 1);
  float x = init_h[d];
  float h = (x >= 0.f) ? (x + 0.5f) : sigm(x);  // h0 = g(init_h)
#pragma unroll
  for (int q = 0; q < NCHUNK; ++q) {
    cH[q * NCH + c] = h;                        // h at START of chunk q
    h = fmaf(cA[q * NCH + c], h, cB[q * NCH + c]);
  }
}

__global__ void scanC(const uint32_t* __restrict__ zg, const float* __restrict__ cH,
                      _Float16* __restrict__ hh, float* __restrict__ out_tail) {
  int gidx = blockIdx.x * 256 + threadIdx.x;
  int q = gidx >> 13, c = gidx & (NCH - 1);
  int b = c >> 11, d = c & (DIN - 1);
  size_t base = ((size_t)b * SS + q * CLEN) * DIN + d;
  float h = cH[q * NCH + c];
#pragma unroll 4
  for (int t = 0; t < CLEN; ++t) {
    uint32_t v = zg[base + (size_t)t * DIN];
    float z = h_lo(v), g = h_hi(v);
    h = fmaf(z, g - h, h);
    hh[base + (size_t)t * DIN] = (_Float16)h;
  }
  if (q == NCHUNK - 1) {
    out_tail[c] = h;             // next_hidden
    out_tail[NCH + c] = logf(h); // next_log_hidden
  }
}

// ---------------- GEMM2: out_h @ W2 + b2 (128x128, ring-2) -----------------
// Ring-2 both sides: 32KB LDS -> 4 blocks/CU (128KB, safe margin). Grid is
// 1024 blocks = exactly one co-resident generation at 4/CU. Distance-1
// prefetch => the wait is vmcnt(0), but those loads are a full K-step
// (~1us) old -- drain is free. __launch_bounds__(256,4) pins VGPR<=128.
// Natural raster order (see gemm1 comment).
__global__ __launch_bounds__(256, 4) void gemm2k(
    const _Float16* __restrict__ hh, const _Float16* __restrict__ w2t,
    const float* __restrict__ b2, float* __restrict__ out) {
  __shared__ _Float16 As[2][128 * 32];   // 2 x 8KB
  __shared__ _Float16 Bs[2][128 * 32];   // 2 x 8KB ; 32KB total

  const int tid = threadIdx.x;
  const int wave = tid >> 6, lane = tid & 63;
  const int wm = wave >> 1, wn = wave & 1;     // 2x2 waves: 64x64 each
  const int m0 = blockIdx.y * 128;
  const int n0 = blockIdx.x * 128;
  const int lrow = lane >> 2;
  const int lk = (((lane & 3) ^ ((lrow >> 1) & 3)) * 8);   // conflict-free swz (see gemm1)
  const int roff = ((((lane & 15) << 2) | ((lane >> 4) ^ ((lane >> 1) & 3))) * 8);

  const _Float16* pA0 = hh + (size_t)(m0 + (wave * 2 + 0) * 16 + lrow) * K2 + lk;
  const _Float16* pA1 = pA0 + (size_t)16 * K2;
  const _Float16* pB0 = w2t + (size_t)(n0 + (wave * 2 + 0) * 16 + lrow) * K2 + lk;
  const _Float16* pB1 = pB0 + (size_t)16 * K2;

  floatx4 acc[4][4] = {};

  // prologue: stage tile 0 into buf 0
  gload16(pA0, &As[0][(wave * 2 + 0) * 512]);
  gload16(pA1, &As[0][(wave * 2 + 1) * 512]);
  gload16(pB0, &Bs[0][(wave * 2 + 0) * 512]);
  gload16(pB1, &Bs[0][(wave * 2 + 1) * 512]);
  pA0 += 32; pA1 += 32; pB0 += 32; pB1 += 32;

#define G2_STEP(rb, sb)                                                         \
  do {                                                                          \
    asm volatile("s_waitcnt vmcnt(0)" ::: "memory");                            \
    __builtin_amdgcn_s_barrier();                                               \
    asm volatile("" ::: "memory");                                              \
    gload16(pA0, &As[sb][(wave * 2 + 0) * 512]);                                \
    gload16(pA1, &As[sb][(wave * 2 + 1) * 512]);                                \
    gload16(pB0, &Bs[sb][(wave * 2 + 0) * 512]);                                \
    gload16(pB1, &Bs[sb][(wave * 2 + 1) * 512]);                                \
    pA0 += 32; pA1 += 32; pB0 += 32; pB1 += 32;                                 \
    half8 af[4], bfr[4];                                                        \
    _Pragma("unroll")                                                           \
    for (int mi = 0; mi < 4; ++mi)                                              \
      af[mi] = *(const half8*)(&As[rb][(wm * 4 + mi) * 512 + roff]);            \
    _Pragma("unroll")                                                           \
    for (int ni = 0; ni < 4; ++ni)                                              \
      bfr[ni] = *(const half8*)(&Bs[rb][(wn * 4 + ni) * 512 + roff]);           \
    _Pragma("unroll")                                                           \
    for (int mi = 0; mi < 4; ++mi)                                              \
      _Pragma("unroll")                                                         \
      for (int ni = 0; ni < 4; ++ni)                                            \
        acc[mi][ni] = __builtin_amdgcn_mfma_f32_16x16x32_f16(                   \
            af[mi], bfr[ni], acc[mi][ni], 0, 0, 0);                             \
  } while (0)

  // 64 K-tiles; tile t reads buf t&1, stages t+1 -> (t+1)&1
  for (int it2 = 0; it2 < 32; ++it2) {
    G2_STEP(0, 1);
    G2_STEP(1, 0);
  }
#undef G2_STEP

#pragma unroll
  for (int ni = 0; ni < 4; ++ni) {
    int n = n0 + wn * 64 + ni * 16 + (lane & 15);
    float bias = b2[n];
#pragma unroll
    for (int mi = 0; mi < 4; ++mi) {
#pragma unroll
      for (int r = 0; r < 4; ++r) {
        int m = m0 + wm * 64 + mi * 16 + (lane >> 4) * 4 + r;
        out[(size_t)m * N2 + n] = acc[mi][ni][r] + bias;
      }
    }
  }
}

// ---------------- launch ----------------

extern "C" void kernel_launch(void* const* d_in, const int* in_sizes, int n_in,
                              void* d_out, int out_size, void* d_ws, size_t ws_size,
                              hipStream_t stream) {
  const float* x      = (const float*)d_in[0];
  const float* W1     = (const float*)d_in[1];
  const float* b1     = (const float*)d_in[2];
  const float* W2     = (const float*)d_in[3];
  const float* b2     = (const float*)d_in[4];
  const float* init_h = (const float*)d_in[5];
  float* out = (float*)d_out;

  char* w = (char*)d_ws;
  _Float16* xh  = (_Float16*)w; w += (size_t)MTOT * K1 * 2;       // 32 MB
  _Float16* w1t = (_Float16*)w; w += (size_t)3 * DIN * K1 * 2;    // 12 MB
  _Float16* w2t = (_Float16*)w; w += (size_t)N2 * K2 * 2;         // 4 MB
  uint32_t* zg  = (uint32_t*)w; w += (size_t)MTOT * DIN * 4;      // 128 MB
  _Float16* hh  = (_Float16*)w; w += (size_t)MTOT * DIN * 2;      // 64 MB
  float* cA = (float*)w; w += (size_t)NCH * NCHUNK * 4;
  float* cB = (float*)w; w += (size_t)NCH * NCHUNK * 4;
  float* cH = (float*)w; w += (size_t)NCH * NCHUNK * 4;

  f32_to_f16_vec<<<dim3(MTOT * K1 / 1024), dim3(256), 0, stream>>>(x, xh);
  transpose_cvt<<<dim3(3 * DIN / 32, K1 / 32), dim3(32, 8), 0, stream>>>(W1, w1t, K1, 3 * DIN);
  transpose_cvt<<<dim3(N2 / 32, K2 / 32), dim3(32, 8), 0, stream>>>(W2, w2t, K2, N2);

  gemm1_fused<<<dim3(DIN / 64, MTOT / 128), dim3(256), 0, stream>>>(xh, w1t, b1, zg);

  scanA<<<dim3(NCH * NCHUNK / 256), dim3(256), 0, stream>>>(zg, cA, cB);
  scanB<<<dim3(NCH / 256), dim3(256), 0, stream>>>(cA, cB, init_h, cH);
  scanC<<<dim3(NCH * NCHUNK / 256), dim3(256), 0, stream>>>(zg, cH, hh, out + (size_t)MTOT * DD);

  gemm2k<<<dim3(N2 / 128, MTOT / 128), dim3(256), 0, stream>>>(hh, w2t, b2, out);
}